// Round 4
// baseline (209.275 us; speedup 1.0000x reference)
//
#include <hip/hip_runtime.h>
#include <stdint.h>

// ---------------- problem constants ----------------
#define S_LEN 256
#define OUT1  262      // S + 7 - 1
#define K1SEL 131      // ceil((2-1)/2 * 262)
#define OUT2  135      // 131 + 5 - 1
// ws layout (floats)
#define W1T_OFF 0          // w1t[d][k][f]      64*7*8   = 3584
#define W2T_OFF 3584       // w2t[g][ic][k][f2] 32*8*5*16= 20480
#define B1C_OFF 24064      // b1c[r2][f]        32*8
#define B2C_OFF 24320      // b2c[r3][f2]       16*16
#define WREG    1120       // floats per wave LDS region

typedef float v2f __attribute__((ext_vector_type(2)));
__device__ __forceinline__ v2f fma2(v2f a, v2f b, v2f c) {
    return __builtin_elementwise_fma(a, b, c);   // -> v_pk_fma_f32 (exact fma/lane)
}

__device__ __forceinline__ int lane_prefix(unsigned long long m) {
    return __builtin_amdgcn_mbcnt_hi((uint32_t)(m >> 32),
           __builtin_amdgcn_mbcnt_lo((uint32_t)m, 0));
}
__device__ __forceinline__ uint32_t f2ord(float x) {
    uint32_t b = __float_as_uint(x);
    return (b & 0x80000000u) ? ~b : (b | 0x80000000u);
}
__device__ __forceinline__ float ord2f(uint32_t s) {
    uint32_t b = (s & 0x80000000u) ? (s & 0x7FFFFFFFu) : ~s;
    return __uint_as_float(b);
}
// tanh via hw rcp: (e-1)*rcp(e+1), e=exp(2x). applied strictly AFTER selection.
__device__ __forceinline__ float fast_tanh(float x) {
    float e = __expf(2.0f * x);
    return (e - 1.0f) * __builtin_amdgcn_rcpf(e + 1.0f);
}
typedef unsigned long long u64;
__device__ __forceinline__ u64 shflx64(u64 v, int m) {
    uint32_t lo = (uint32_t)__shfl_xor((int)(uint32_t)v, m, 64);
    uint32_t hi = (uint32_t)__shfl_xor((int)(uint32_t)(v >> 32), m, 64);
    return ((u64)hi << 32) | lo;
}
__device__ __forceinline__ u64 maxu64(u64 a, u64 b) { return a > b ? a : b; }
__device__ __forceinline__ u64 minu64(u64 a, u64 b) { return a < b ? a : b; }

// ------------- prep: transpose weights / fold biases into ws; init out with bias -------------
extern "C" __global__ void dcnn_prep(const float* __restrict__ w1, const float* __restrict__ b1,
                                     const float* __restrict__ w2, const float* __restrict__ b2,
                                     const float* __restrict__ fcb, float* __restrict__ out,
                                     float* __restrict__ ws) {
    int i = blockIdx.x * 256 + threadIdx.x;   // 96*256 == 24576
    if (i < 3072) out[i] = fcb[i % 6];        // out[s*6+n] = fcb[n]
    if (i < W2T_OFF) {                        // w1t[d][k][f] = w1[(d*8+f)*7 + k]
        int d = i / 56, r = i % 56, k = r / 8, f = r % 8;
        ws[i] = w1[(d * 8 + f) * 7 + k];
    } else if (i < B1C_OFF) {                 // w2t[g][ic][k][f2] = w2[((g*16+f2)*8+ic)*5+k]
        int q = i - W2T_OFF;
        int g = q / 640, r = q % 640;
        int ic = r / 80, r2 = r % 80;
        int k = r2 / 16, f2 = r2 % 16;
        ws[i] = w2[((g * 16 + f2) * 8 + ic) * 5 + k];
    } else if (i < B1C_OFF + 256 && i >= B1C_OFF) { // b1c[r2][f] = b1[2r2*8+f] + b1[(2r2+1)*8+f]
        int q = i - B1C_OFF;
        int r2 = q / 8, f = q % 8;
        ws[i] = b1[(2 * r2) * 8 + f] + b1[(2 * r2 + 1) * 8 + f];
    } else {                                  // b2c[r3][f2]
        int q = i - B2C_OFF;
        int r3 = q / 16, f2 = q % 16;
        ws[i] = b2[(2 * r3) * 16 + f2] + b2[(2 * r3 + 1) * 16 + f2];
    }
}

// ------------- main: one wave = one (slice, half) task; R17 structure -------------
// Block = 256 thr (4 waves) = 2 slices x 2 halves of ONE sample; grid 4096.
// R17 (issue-slot diet; R16 showed occupancy 70% w/ VALUBusy flat 67% -> pure
// instruction-count bound): (a) conv2 restructured d-split -> T-SPLIT: each
// wave computes the FULL fold sum (both groups g=2sl,2sl+1, reading both p1
// regions) over half the t-range (rs0: t0..63 + tail 128..134; rs1: 64..127).
// Same fma/window-load count, but the 3-step cross-wave fold exchange
// (~135 LDS+VALU ops on !rs + 1 barrier + skew) collapses to 18 result writes.
// (b) compaction writes raw ORDINAL bits; ord2f fused into the dense tanh
// pass (guards = -0.0f = ord(0.0) so tanh sees 0). (c) top-4 scan fully
// unrolled: 16 clean imm-offset iters + 1 masked (kills per-iter clamp).
// (d) x read direct from global (L1-hit), xs[] + its barrier removed.
// R16: conv2 per-lane tail; radix 16-bit fused 8-ch. R14: no-refine <=>
// count(u>=pre)==K via ge. R12: rcp-tanh dense post-pass. R11: v_pk_fma_f32.
// R9: waves_per_eu(4,8). R3: all acc/u indices compile-time.
extern "C" __global__
__attribute__((amdgpu_flat_work_group_size(256, 256), amdgpu_waves_per_eu(4, 8)))
void dcnn_main(const int* __restrict__ x, const float* __restrict__ emb,
               const float* __restrict__ fcw, const float* __restrict__ ws,
               float* __restrict__ out) {
    __shared__ float uni[4 * WREG];       // 17920 B
    __shared__ float p2loc[128];          // this block's 128 FC features (raw, pre-tanh)
    __shared__ float fred[4][3];

    const int tid    = threadIdx.x;
    const int lane   = tid & 63;
    const int wv     = __builtin_amdgcn_readfirstlane(tid >> 6);  // 0..3
    const int sample = blockIdx.x >> 3;
    const int q8     = blockIdx.x & 7;
    const int sl     = q8 * 2 + (wv >> 1);   // global slice r3 in [0,16)
    const int rs     = wv & 1;               // which t-half of conv2 this wave owns

    const float* w1t = ws + W1T_OFF;
    const float* w2t = ws + W2T_OFF;
    const float* b1c = ws + B1C_OFF;
    const float* b2c = ws + B2C_OFF;

    float*  reg   = uni + wv * WREG;
    float2* rowsW = (float2*)reg;          // 272 float2 = 544 floats
    float*  p1w   = reg;                   // [f:8][140]

    // ---- guards + stage 2 embedding rows (d = 4sl+2rs, +1) as float2 per j ----
    if (lane < 8) {
        rowsW[lane]       = make_float2(0.f, 0.f);
        rowsW[264 + lane] = make_float2(0.f, 0.f);
    }
    const int dbase = 4 * sl + 2 * rs;
    const int* xrow = x + sample * S_LEN;
#pragma unroll
    for (int m = 0; m < 4; ++m) {
        int j  = lane + 64 * m;            // input pos 0..255
        int xi = xrow[j];                  // L1/L2-hit (shared across waves/blocks)
        rowsW[8 + j] = *(const float2*)(emb + (size_t)xi * 64 + dbase);
    }

    // ---- conv1 (K=7, depthwise) + fold: 8 channels as 4 packed pairs ----
    v2f acc2[4][5];
#pragma unroll
    for (int j = 0; j < 4; ++j) {
        v2f bz = *(const v2f*)(b1c + (2 * sl + rs) * 8 + 2 * j);
#pragma unroll
        for (int m = 0; m < 5; ++m) acc2[j][m] = bz;
    }
    int tA[5];
#pragma unroll
    for (int m = 0; m < 5; ++m) { int t = lane + 64 * m; tA[m] = (t < OUT1) ? t : (OUT1 - 1); }

#pragma unroll 1
    for (int k = 0; k < 7; ++k) {
        v2f wa[4], wb[4];
#pragma unroll
        for (int j = 0; j < 4; ++j) {
            wa[j] = *(const v2f*)(w1t + (dbase * 7 + k) * 8 + 2 * j);
            wb[j] = *(const v2f*)(w1t + ((dbase + 1) * 7 + k) * 8 + 2 * j);
        }
#pragma unroll
        for (int m = 0; m < 5; ++m) {
            float2 v = rowsW[tA[m] + 2 + k];   // j = t-6+k, +8 guard offset
            v2f vx = { v.x, v.x };
            v2f vy = { v.y, v.y };
#pragma unroll
            for (int j = 0; j < 4; ++j) {
                acc2[j][m] = fma2(wa[j], vx, acc2[j][m]);
                acc2[j][m] = fma2(wb[j], vy, acc2[j][m]);
            }
        }
    }

    // ---- p1 guards (rows region dead; p1 aliases it). 64 lanes = 8 ch x 8 slots ----
    // guard value = -0.0f == bits of ord(0.0): tanh pass ord2f's it back to +0.
    {
        int c = lane >> 3, j = lane & 7;
        int pos = (j < 4) ? j : (131 + j);
        p1w[c * 140 + pos] = __uint_as_float(0x80000000u);
    }

    // ---- exact order-preserving top-131 per channel (fused 16-bit radix) ----
    uint32_t uu[4][2][5];
#pragma unroll
    for (int cp = 0; cp < 4; ++cp) {
#pragma unroll
        for (int m = 0; m < 4; ++m) {          // t = lane+64m < 256 < OUT1 always
            uu[cp][0][m] = f2ord(acc2[cp][m].x);
            uu[cp][1][m] = f2ord(acc2[cp][m].y);
        }
        uu[cp][0][4] = (lane < 6) ? f2ord(acc2[cp][4].x) : 0u;   // t=lane+256 < 262
        uu[cp][1][4] = (lane < 6) ? f2ord(acc2[cp][4].y) : 0u;
    }
    uint32_t pre[8];
    int ge[8];                                 // count(u>=pre) at last accept
#pragma unroll
    for (int c = 0; c < 8; ++c) { pre[c] = 0u; ge[c] = 0x7FFFFFFF; }
#pragma unroll 1
    for (int bit = 31; bit >= 16; --bit) {
#pragma unroll
        for (int c = 0; c < 8; ++c) {
            uint32_t cand = pre[c] | (1u << bit);
            int n = 0;
#pragma unroll
            for (int m = 0; m < 5; ++m)
                n += __popcll(__ballot(uu[c >> 1][c & 1][m] >= cand));
            if (n >= K1SEL) { pre[c] = cand; ge[c] = n; }
        }
    }
    // ---- per-pair compaction: writes ORDINAL bits (ord2f+tanh later) ----
#pragma unroll
    for (int cp = 0; cp < 4; ++cp) {
        uint32_t preA = pre[2 * cp], preB = pre[2 * cp + 1];
        float* dstA = p1w + (2 * cp) * 140 + 4;
        float* dstB = p1w + (2 * cp + 1) * 140 + 4;
        if (ge[2 * cp] == K1SEL && ge[2 * cp + 1] == K1SEL) {
            // common path: class boundary exact -> keep = (u >= pre), all ties kept
            int kpA = 0, kpB = 0;
#pragma unroll
            for (int m = 0; m < 5; ++m) {
                unsigned long long kmA = __ballot(uu[cp][0][m] >= preA);
                unsigned long long kmB = __ballot(uu[cp][1][m] >= preB);
                int posA = kpA + lane_prefix(kmA);     // order-preserving compaction
                int posB = kpB + lane_prefix(kmB);
                if (uu[cp][0][m] >= preA) dstA[posA] = __uint_as_float(uu[cp][0][m]);
                if (uu[cp][1][m] >= preB) dstB[posB] = __uint_as_float(uu[cp][1][m]);
                kpA += __popcll(kmA); kpB += __popcll(kmB);
            }
        } else {
            // rare path: boundary inside a 16-bit class -> refine low bits fully
#pragma unroll 1
            for (int bit = 15; bit >= 0; --bit) {
                uint32_t cA = preA | (1u << bit);
                uint32_t cB = preB | (1u << bit);
                int na = 0, nb = 0;
#pragma unroll
                for (int m = 0; m < 5; ++m) {
                    na += __popcll(__ballot(uu[cp][0][m] >= cA));
                    nb += __popcll(__ballot(uu[cp][1][m] >= cB));
                }
                if (na >= K1SEL) preA = cA;
                if (nb >= K1SEL) preB = cB;
            }
            int cgtA = 0, cgtB = 0;
#pragma unroll
            for (int m = 0; m < 5; ++m) {
                cgtA += __popcll(__ballot(uu[cp][0][m] > preA));
                cgtB += __popcll(__ballot(uu[cp][1][m] > preB));
            }
            const int needA = K1SEL - cgtA;            // #ties kept (earliest t first)
            const int needB = K1SEL - cgtB;
            int eqA = 0, kpA = 0, eqB = 0, kpB = 0;
#pragma unroll
            for (int m = 0; m < 5; ++m) {
                unsigned long long emA = __ballot(uu[cp][0][m] == preA);
                unsigned long long emB = __ballot(uu[cp][1][m] == preB);
                int erA = eqA + lane_prefix(emA);
                int erB = eqB + lane_prefix(emB);
                bool keepA = (uu[cp][0][m] > preA) || ((uu[cp][0][m] == preA) && (erA < needA));
                bool keepB = (uu[cp][1][m] > preB) || ((uu[cp][1][m] == preB) && (erB < needB));
                unsigned long long kmA = __ballot(keepA);
                unsigned long long kmB = __ballot(keepB);
                int posA = kpA + lane_prefix(kmA);
                int posB = kpB + lane_prefix(kmB);
                if (keepA) dstA[posA] = __uint_as_float(uu[cp][0][m]);
                if (keepB) dstB[posB] = __uint_as_float(uu[cp][1][m]);
                eqA += __popcll(emA); kpA += __popcll(kmA);
                eqB += __popcll(emB); kpB += __popcll(kmB);
            }
        }
    }

    // ---- dense ord2f+tanh post-pass over the whole p1 region (1120 floats) ----
    // guards are ord(0)->0; slot 139 of each channel holds garbage, never consumed.
#pragma unroll
    for (int i = 0; i < 17; ++i) {
        int idx = lane + 64 * i;
        p1w[idx] = fast_tanh(ord2f(__float_as_uint(p1w[idx])));
    }
    if (lane < 32) {
        int idx = lane + 64 * 17;
        p1w[idx] = fast_tanh(ord2f(__float_as_uint(p1w[idx])));
    }

    __syncthreads();   // partner wave's p1 ready (t-split conv2 reads both regions)

    // ---- conv2 t-split: this wave computes the FULL fold sum (groups 2sl and
    // 2sl+1) over its t-range. rs0: t=0..63 + tail 128..134; rs1: t=64..127. ----
    const float* pairp = uni + (wv & ~1) * WREG;   // [0..WREG)=group 2sl, [WREG..)=2sl+1
    const v2f*   b2v   = (const v2f*)(b2c + sl * 16);
    const int    t0    = rs ? 64 : 0;
    v2f acc[8];
#pragma unroll
    for (int j = 0; j < 8; ++j) acc[j] = b2v[j];   // folded bias, once per (t,f2)

#pragma unroll 1
    for (int hc = 0; hc < 2; ++hc) {
        const float* psrc = pairp + hc * WREG;
        const float* wg   = w2t + (2 * sl + hc) * 640;
#pragma unroll 1
        for (int ic = 0; ic < 8; ++ic) {
            const float* src = psrc + ic * 140 + t0 + lane;
            float win[5];
#pragma unroll
            for (int k = 0; k < 5; ++k) win[k] = src[k];
#pragma unroll
            for (int k = 0; k < 5; ++k) {
                const v2f* wv2 = (const v2f*)(wg + (ic * 5 + k) * 16);
                v2f s = { win[k], win[k] };
#pragma unroll
                for (int j = 0; j < 8; ++j) acc[j] = fma2(wv2[j], s, acc[j]);
            }
        }
    }

    // per-lane tail t=128..134 (rs0 wave only; lanes 0..55: tt=lane>>3, pair tj)
    const int tt = lane >> 3;
    const int tj = lane & 7;
    v2f at = b2v[tj];
    if (!rs) {
#pragma unroll 1
        for (int hc = 0; hc < 2; ++hc) {
            const float* tsrc = pairp + hc * WREG + 128 + tt;
            const float* tw   = w2t + (2 * sl + hc) * 640 + 2 * tj;
#pragma unroll
            for (int ic = 0; ic < 8; ++ic) {
#pragma unroll
                for (int k = 0; k < 5; ++k) {
                    float sv = tsrc[ic * 140 + k];
                    v2f w = *(const v2f*)(tw + (ic * 5 + k) * 16);
                    v2f sb = { sv, sv };
                    at = fma2(w, sb, at);
                }
            }
        }
    }

    __syncthreads();   // all p1 reads done -> pair region reusable as scr
    float* scr = uni + (wv & ~1) * WREG;     // [f2:16][137] final fold sums
#pragma unroll
    for (int j = 0; j < 8; ++j) {
        scr[(2 * j) * 137 + t0 + lane]     = acc[j].x;
        scr[(2 * j + 1) * 137 + t0 + lane] = acc[j].y;
    }
    if (!rs && lane < 56) {
        scr[(2 * tj) * 137 + 128 + tt]     = at.x;
        scr[(2 * tj + 1) * 137 + 128 + tt] = at.y;
    }
    __syncthreads();                          // sums visible to both waves

    // ---- top-4 (value desc, tie -> lower t): BOTH waves, 8 lanes per f2 ----
    // 64-bit key = (f2ord(v)<<32) | (0xFFFFFFFF - t); desc == value desc, tie t asc.
    {
        const int f2o = (lane >> 3) + 8 * rs;  // this wave's 8 f2 channels
        const int seg = lane & 7;              // segment of 17 (last has 16)
        const int tstart = seg * 17;
        const float* src = scr + f2o * 137 + tstart;
        const uint32_t tb = 0xFFFFFFFFu - (uint32_t)tstart;
        u64 L0 = 0, L1 = 0, L2 = 0, L3 = 0;    // sentinels (lose to any finite)
#pragma unroll
        for (int i = 0; i < 17; ++i) {
            float v = src[i];                  // i=16 for seg==7 reads in-row slack
            u64 kk = ((u64)f2ord(v) << 32) | (u64)(tb - (uint32_t)i);
            if (i == 16 && seg == 7) kk = 0;   // only masked case
            bool b0 = kk > L0, b1 = kk > L1, b2 = kk > L2, b3 = kk > L3;
            L3 = b3 ? (b2 ? L2 : kk) : L3;
            L2 = b2 ? (b1 ? L1 : kk) : L2;
            L1 = b1 ? (b0 ? L0 : kk) : L1;
            L0 = b0 ? kk : L0;
        }
        // merge 8 segments: 3 shfl rounds; r_i = min_{j+l=i} max(A_j,B_l)
#pragma unroll
        for (int d = 1; d <= 4; d <<= 1) {
            u64 M0 = shflx64(L0, d), M1 = shflx64(L1, d);
            u64 M2 = shflx64(L2, d), M3 = shflx64(L3, d);
            u64 r0 = maxu64(L0, M0);
            u64 r1 = minu64(maxu64(L0, M1), maxu64(L1, M0));
            u64 r2 = minu64(minu64(maxu64(L0, M2), maxu64(L1, M1)), maxu64(L2, M0));
            u64 r3k = minu64(minu64(maxu64(L0, M3), maxu64(L1, M2)),
                             minu64(maxu64(L2, M1), maxu64(L3, M0)));
            L0 = r0; L1 = r1; L2 = r2; L3 = r3k;
        }
        if (seg == 0) {
            // reorder by t ascending == low-32 word descending; emit raw (tanh in FC)
#define CSW2(a, bb) { if ((uint32_t)(bb) > (uint32_t)(a)) { u64 tt2 = (a); (a) = (bb); (bb) = tt2; } }
            CSW2(L0, L1); CSW2(L2, L3); CSW2(L0, L2); CSW2(L1, L3); CSW2(L1, L2);
#undef CSW2
            float* qp = &p2loc[(wv >> 1) * 64 + f2o * 4];
            qp[0] = ord2f((uint32_t)(L0 >> 32));
            qp[1] = ord2f((uint32_t)(L1 >> 32));
            qp[2] = ord2f((uint32_t)(L2 >> 32));
            qp[3] = ord2f((uint32_t)(L3 >> 32));
        }
    }
    __syncthreads();

    // ---- FC partials over 128 features, all 4 waves (3 classes x 64 feats each) ----
    {
        const int nb = (wv >> 1) * 3;          // class base: 0 or 3
        const int fh = (wv & 1) * 64;          // feature half
        float pv = fast_tanh(p2loc[fh + lane]);
#pragma unroll
        for (int i = 0; i < 3; ++i) {
            float s = pv * fcw[(nb + i) * 1024 + q8 * 128 + fh + lane];
#pragma unroll
            for (int off = 32; off > 0; off >>= 1) s += __shfl_xor(s, off, 64);
            if (lane == 0) fred[wv][i] = s;
        }
    }
    __syncthreads();
    if (tid < 6) {
        float v = (tid < 3) ? (fred[0][tid] + fred[1][tid])
                            : (fred[2][tid - 3] + fred[3][tid - 3]);
        atomicAdd(&out[sample * 6 + tid], v);
    }
}

extern "C" void kernel_launch(void* const* d_in, const int* in_sizes, int n_in,
                              void* d_out, int out_size, void* d_ws, size_t ws_size,
                              hipStream_t stream) {
    (void)in_sizes; (void)n_in; (void)out_size; (void)ws_size;
    const int*   x   = (const int*)d_in[0];
    const float* emb = (const float*)d_in[1];
    const float* w1  = (const float*)d_in[2];
    const float* b1  = (const float*)d_in[3];
    const float* w2  = (const float*)d_in[4];
    const float* b2  = (const float*)d_in[5];
    const float* fcw = (const float*)d_in[6];
    const float* fcb = (const float*)d_in[7];
    float* outp = (float*)d_out;
    float* wsf  = (float*)d_ws;   // weights+biases: 24576 floats

    dcnn_prep<<<96, 256, 0, stream>>>(w1, b1, w2, b2, fcb, outp, wsf);
    dcnn_main<<<4096, 256, 0, stream>>>(x, emb, fcw, wsf, outp);
}

// Round 5
// 205.788 us; speedup vs baseline: 1.0169x; 1.0169x over previous
//
#include <hip/hip_runtime.h>
#include <stdint.h>

// ---------------- problem constants ----------------
#define S_LEN 256
#define OUT1  262      // S + 7 - 1
#define K1SEL 131      // ceil((2-1)/2 * 262)
#define OUT2  135      // 131 + 5 - 1
// ws layout (floats)
#define W1T_OFF 0          // w1t[d][k][f]      64*7*8   = 3584
#define W2T_OFF 3584       // w2t[g][ic][k][f2] 32*8*5*16= 20480
#define B1C_OFF 24064      // b1c[r2][f]        32*8
#define B2C_OFF 24320      // b2c[r3][f2]       16*16
#define WREG    1120       // floats per wave LDS region

typedef float v2f __attribute__((ext_vector_type(2)));
__device__ __forceinline__ v2f fma2(v2f a, v2f b, v2f c) {
    return __builtin_elementwise_fma(a, b, c);   // -> v_pk_fma_f32 (exact fma/lane)
}

__device__ __forceinline__ int lane_prefix(unsigned long long m) {
    return __builtin_amdgcn_mbcnt_hi((uint32_t)(m >> 32),
           __builtin_amdgcn_mbcnt_lo((uint32_t)m, 0));
}
__device__ __forceinline__ uint32_t f2ord(float x) {
    uint32_t b = __float_as_uint(x);
    return (b & 0x80000000u) ? ~b : (b | 0x80000000u);
}
__device__ __forceinline__ float ord2f(uint32_t s) {
    uint32_t b = (s & 0x80000000u) ? (s & 0x7FFFFFFFu) : ~s;
    return __uint_as_float(b);
}
// tanh via hw rcp: (e-1)*rcp(e+1), e=exp(2x). applied strictly AFTER selection.
__device__ __forceinline__ float fast_tanh(float x) {
    float e = __expf(2.0f * x);
    return (e - 1.0f) * __builtin_amdgcn_rcpf(e + 1.0f);
}
typedef unsigned long long u64;
__device__ __forceinline__ u64 shflx64(u64 v, int m) {
    uint32_t lo = (uint32_t)__shfl_xor((int)(uint32_t)v, m, 64);
    uint32_t hi = (uint32_t)__shfl_xor((int)(uint32_t)(v >> 32), m, 64);
    return ((u64)hi << 32) | lo;
}
__device__ __forceinline__ u64 maxu64(u64 a, u64 b) { return a > b ? a : b; }
__device__ __forceinline__ u64 minu64(u64 a, u64 b) { return a < b ? a : b; }

// ------------- prep: transpose weights / fold biases into ws; init out with bias -------------
extern "C" __global__ void dcnn_prep(const float* __restrict__ w1, const float* __restrict__ b1,
                                     const float* __restrict__ w2, const float* __restrict__ b2,
                                     const float* __restrict__ fcb, float* __restrict__ out,
                                     float* __restrict__ ws) {
    int i = blockIdx.x * 256 + threadIdx.x;   // 96*256 == 24576
    if (i < 3072) out[i] = fcb[i % 6];        // out[s*6+n] = fcb[n]
    if (i < W2T_OFF) {                        // w1t[d][k][f] = w1[(d*8+f)*7 + k]
        int d = i / 56, r = i % 56, k = r / 8, f = r % 8;
        ws[i] = w1[(d * 8 + f) * 7 + k];
    } else if (i < B1C_OFF) {                 // w2t[g][ic][k][f2] = w2[((g*16+f2)*8+ic)*5+k]
        int q = i - W2T_OFF;
        int g = q / 640, r = q % 640;
        int ic = r / 80, r2 = r % 80;
        int k = r2 / 16, f2 = r2 % 16;
        ws[i] = w2[((g * 16 + f2) * 8 + ic) * 5 + k];
    } else if (i < B2C_OFF) {                 // b1c[r2][f] = b1[2r2*8+f] + b1[(2r2+1)*8+f]
        int q = i - B1C_OFF;
        int r2 = q / 8, f = q % 8;
        ws[i] = b1[(2 * r2) * 8 + f] + b1[(2 * r2 + 1) * 8 + f];
    } else {                                  // b2c[r3][f2]
        int q = i - B2C_OFF;
        int r3 = q / 16, f2 = q % 16;
        ws[i] = b2[(2 * r3) * 16 + f2] + b2[(2 * r3 + 1) * 16 + f2];
    }
}

// ------------- main: one wave = one (slice, rs-half) task; R18 structure -------------
// Block = 256 thr (4 waves) = 2 slices x 2 rs-halves of ONE sample; grid 4096.
// R18 = R16 chassis + R17's safe diet items. R17 post-mortem: conv2 t-split
// blew VGPR 32->60, occupancy 70->38%, dur 134.6->144.3 -> occupancy x issue
// density rules; REVERTED to R16's d-split conv2 + fold exchange. Kept from
// R17: (b) compaction writes raw ORDINAL bits, ord2f fused into dense tanh
// pass (guards = -0.0f = ord(0.0)); (c) top-4 scan fully unrolled, only
// i==16&&seg==7 masked (reads in-row slack 135/136 < 137); (d) x read direct
// from global (L1-hit), xs[] + barrier removed.
// R16: conv2 m=2 chunk -> 56-lane per-lane tail; radix 16-bit fused 8-ch;
// FC over 4 waves. R14: no-refine <=> count(u>=pre)==K via ge. R13: 128thr
// blocks regressed. R12: rcp-tanh dense post-pass. R11: v_pk_fma_f32.
// R9: waves_per_eu(4,8). R3: all acc/u indices compile-time.
extern "C" __global__
__attribute__((amdgpu_flat_work_group_size(256, 256), amdgpu_waves_per_eu(4, 8)))
void dcnn_main(const int* __restrict__ x, const float* __restrict__ emb,
               const float* __restrict__ fcw, const float* __restrict__ ws,
               float* __restrict__ out) {
    __shared__ float uni[4 * WREG];       // 17920 B
    __shared__ float p2loc[128];          // this block's 128 FC features (raw, pre-tanh)
    __shared__ float fred[4][3];

    const int tid    = threadIdx.x;
    const int lane   = tid & 63;
    const int wv     = __builtin_amdgcn_readfirstlane(tid >> 6);  // 0..3
    const int sample = blockIdx.x >> 3;
    const int q8     = blockIdx.x & 7;
    const int sl     = q8 * 2 + (wv >> 1);   // global slice r3 in [0,16)
    const int rs     = wv & 1;               // which half of the fold pair

    const float* w1t = ws + W1T_OFF;
    const float* w2t = ws + W2T_OFF;
    const float* b1c = ws + B1C_OFF;
    const float* b2c = ws + B2C_OFF;

    float*  reg   = uni + wv * WREG;
    float2* rowsW = (float2*)reg;          // 272 float2 = 544 floats
    float*  p1w   = reg;                   // [f:8][140]

    // ---- guards + stage 2 embedding rows (d = 4sl+2rs, +1) as float2 per j ----
    if (lane < 8) {
        rowsW[lane]       = make_float2(0.f, 0.f);
        rowsW[264 + lane] = make_float2(0.f, 0.f);
    }
    const int dbase = 4 * sl + 2 * rs;
    const int* xrow = x + sample * S_LEN;
#pragma unroll
    for (int m = 0; m < 4; ++m) {
        int j  = lane + 64 * m;            // input pos 0..255
        int xi = xrow[j];                  // coalesced dword, L1/L2-hit across waves
        rowsW[8 + j] = *(const float2*)(emb + (size_t)xi * 64 + dbase);
    }

    // ---- conv1 (K=7, depthwise) + fold: 8 channels as 4 packed pairs ----
    v2f acc2[4][5];
#pragma unroll
    for (int j = 0; j < 4; ++j) {
        v2f bz = *(const v2f*)(b1c + (2 * sl + rs) * 8 + 2 * j);
#pragma unroll
        for (int m = 0; m < 5; ++m) acc2[j][m] = bz;
    }
    int tA[5];
#pragma unroll
    for (int m = 0; m < 5; ++m) { int t = lane + 64 * m; tA[m] = (t < OUT1) ? t : (OUT1 - 1); }

#pragma unroll 1
    for (int k = 0; k < 7; ++k) {
        v2f wa[4], wb[4];
#pragma unroll
        for (int j = 0; j < 4; ++j) {
            wa[j] = *(const v2f*)(w1t + (dbase * 7 + k) * 8 + 2 * j);
            wb[j] = *(const v2f*)(w1t + ((dbase + 1) * 7 + k) * 8 + 2 * j);
        }
#pragma unroll
        for (int m = 0; m < 5; ++m) {
            float2 v = rowsW[tA[m] + 2 + k];   // j = t-6+k, +8 guard offset
            v2f vx = { v.x, v.x };
            v2f vy = { v.y, v.y };
#pragma unroll
            for (int j = 0; j < 4; ++j) {
                acc2[j][m] = fma2(wa[j], vx, acc2[j][m]);
                acc2[j][m] = fma2(wb[j], vy, acc2[j][m]);
            }
        }
    }

    // ---- p1 guards (rows region dead; p1 aliases it). 64 lanes = 8 ch x 8 slots ----
    // guard value = -0.0f == bits of ord(0.0): tanh pass ord2f's it back to +0.
    {
        int c = lane >> 3, j = lane & 7;
        int pos = (j < 4) ? j : (131 + j);
        p1w[c * 140 + pos] = __uint_as_float(0x80000000u);
    }

    // ---- exact order-preserving top-131 per channel (fused 16-bit radix) ----
    uint32_t uu[4][2][5];
#pragma unroll
    for (int cp = 0; cp < 4; ++cp) {
#pragma unroll
        for (int m = 0; m < 4; ++m) {          // t = lane+64m < 256 < OUT1 always
            uu[cp][0][m] = f2ord(acc2[cp][m].x);
            uu[cp][1][m] = f2ord(acc2[cp][m].y);
        }
        uu[cp][0][4] = (lane < 6) ? f2ord(acc2[cp][4].x) : 0u;   // t=lane+256 < 262
        uu[cp][1][4] = (lane < 6) ? f2ord(acc2[cp][4].y) : 0u;
    }
    uint32_t pre[8];
    int ge[8];                                 // count(u>=pre) at last accept
#pragma unroll
    for (int c = 0; c < 8; ++c) { pre[c] = 0u; ge[c] = 0x7FFFFFFF; }
#pragma unroll 1
    for (int bit = 31; bit >= 16; --bit) {
#pragma unroll
        for (int c = 0; c < 8; ++c) {
            uint32_t cand = pre[c] | (1u << bit);
            int n = 0;
#pragma unroll
            for (int m = 0; m < 5; ++m)
                n += __popcll(__ballot(uu[c >> 1][c & 1][m] >= cand));
            if (n >= K1SEL) { pre[c] = cand; ge[c] = n; }
        }
    }
    // ---- per-pair compaction: writes ORDINAL bits (ord2f+tanh later) ----
#pragma unroll
    for (int cp = 0; cp < 4; ++cp) {
        uint32_t preA = pre[2 * cp], preB = pre[2 * cp + 1];
        float* dstA = p1w + (2 * cp) * 140 + 4;
        float* dstB = p1w + (2 * cp + 1) * 140 + 4;
        if (ge[2 * cp] == K1SEL && ge[2 * cp + 1] == K1SEL) {
            // common path: class boundary exact -> keep = (u >= pre), all ties kept
            int kpA = 0, kpB = 0;
#pragma unroll
            for (int m = 0; m < 5; ++m) {
                unsigned long long kmA = __ballot(uu[cp][0][m] >= preA);
                unsigned long long kmB = __ballot(uu[cp][1][m] >= preB);
                int posA = kpA + lane_prefix(kmA);     // order-preserving compaction
                int posB = kpB + lane_prefix(kmB);
                if (uu[cp][0][m] >= preA) dstA[posA] = __uint_as_float(uu[cp][0][m]);
                if (uu[cp][1][m] >= preB) dstB[posB] = __uint_as_float(uu[cp][1][m]);
                kpA += __popcll(kmA); kpB += __popcll(kmB);
            }
        } else {
            // rare path: boundary inside a 16-bit class -> refine low bits fully
#pragma unroll 1
            for (int bit = 15; bit >= 0; --bit) {
                uint32_t cA = preA | (1u << bit);
                uint32_t cB = preB | (1u << bit);
                int na = 0, nb = 0;
#pragma unroll
                for (int m = 0; m < 5; ++m) {
                    na += __popcll(__ballot(uu[cp][0][m] >= cA));
                    nb += __popcll(__ballot(uu[cp][1][m] >= cB));
                }
                if (na >= K1SEL) preA = cA;
                if (nb >= K1SEL) preB = cB;
            }
            int cgtA = 0, cgtB = 0;
#pragma unroll
            for (int m = 0; m < 5; ++m) {
                cgtA += __popcll(__ballot(uu[cp][0][m] > preA));
                cgtB += __popcll(__ballot(uu[cp][1][m] > preB));
            }
            const int needA = K1SEL - cgtA;            // #ties kept (earliest t first)
            const int needB = K1SEL - cgtB;
            int eqA = 0, kpA = 0, eqB = 0, kpB = 0;
#pragma unroll
            for (int m = 0; m < 5; ++m) {
                unsigned long long emA = __ballot(uu[cp][0][m] == preA);
                unsigned long long emB = __ballot(uu[cp][1][m] == preB);
                int erA = eqA + lane_prefix(emA);
                int erB = eqB + lane_prefix(emB);
                bool keepA = (uu[cp][0][m] > preA) || ((uu[cp][0][m] == preA) && (erA < needA));
                bool keepB = (uu[cp][1][m] > preB) || ((uu[cp][1][m] == preB) && (erB < needB));
                unsigned long long kmA = __ballot(keepA);
                unsigned long long kmB = __ballot(keepB);
                int posA = kpA + lane_prefix(kmA);
                int posB = kpB + lane_prefix(kmB);
                if (keepA) dstA[posA] = __uint_as_float(uu[cp][0][m]);
                if (keepB) dstB[posB] = __uint_as_float(uu[cp][1][m]);
                eqA += __popcll(emA); kpA += __popcll(kmA);
                eqB += __popcll(emB); kpB += __popcll(kmB);
            }
        }
    }

    // ---- dense ord2f+tanh post-pass over the whole p1 region (1120 floats) ----
    // guards are ord(0)->0; slot 139 holds garbage (possibly NaN after ord2f),
    // only ever read by inactive tail lanes (tt==7, lane>=56 -> result unused).
#pragma unroll
    for (int i = 0; i < 17; ++i) {
        int idx = lane + 64 * i;
        p1w[idx] = fast_tanh(ord2f(__float_as_uint(p1w[idx])));
    }
    if (lane < 32) {
        int idx = lane + 64 * 17;
        p1w[idx] = fast_tanh(ord2f(__float_as_uint(p1w[idx])));
    }

    // ---- conv2 partial: group g = 2sl+rs; 16 f2 as 8 packed pairs ----
    // main chunks m=0,1 (t=0..127, all lanes useful); t=128..134 via per-lane tail.
    const int g = 2 * sl + rs;
    const v2f* b2v = (const v2f*)(b2c + sl * 16);
    v2f a2v[8][2];
#pragma unroll
    for (int j = 0; j < 8; ++j) {
        v2f bz = rs ? (v2f){0.f, 0.f} : b2v[j];   // pre-folded bias counted once
        a2v[j][0] = bz; a2v[j][1] = bz;
    }

#pragma unroll 1
    for (int ic = 0; ic < 8; ++ic) {
        const float* src = p1w + ic * 140;   // logical t' = idx - 4
        float win[2][5];                     // straight-line, all offsets compile-time
#pragma unroll
        for (int m = 0; m < 2; ++m) {
#pragma unroll
            for (int k = 0; k < 5; ++k) win[m][k] = src[lane + 64 * m + k];
        }
#pragma unroll
        for (int k = 0; k < 5; ++k) {
            const v2f* wv2 = (const v2f*)(w2t + ((g * 8 + ic) * 5 + k) * 16);
            v2f s0 = { win[0][k], win[0][k] };
            v2f s1 = { win[1][k], win[1][k] };
#pragma unroll
            for (int j = 0; j < 8; ++j) {
                v2f w = wv2[j];
                a2v[j][0] = fma2(w, s0, a2v[j][0]);
                a2v[j][1] = fma2(w, s1, a2v[j][1]);
            }
        }
    }

    // per-lane tail: lanes 0..55 each own (t = 128+tt, f2-pair tj)
    const int tt = lane >> 3;                // 0..7 (7 = inactive)
    const int tj = lane & 7;
    v2f at = (!rs) ? b2v[tj] : (v2f){0.f, 0.f};
    {
        const float* tsrc0 = p1w + 128 + tt;             // + ic*140 + k (imm)
        const float* tw    = w2t + g * 640 + 2 * tj;     // + (ic*5+k)*16 (imm)
#pragma unroll
        for (int ic = 0; ic < 8; ++ic) {
#pragma unroll
            for (int k = 0; k < 5; ++k) {
                float sv = tsrc0[ic * 140 + k];          // <=139: in-region even for tt=7
                v2f w = *(const v2f*)(tw + (ic * 5 + k) * 16);
                v2f sb = { sv, sv };
                at = fma2(w, sb, at);
            }
        }
    }

    // ---- cross-wave fold (a2 sum) in the pair's dead p1 regions ----
    float* scr = uni + (wv & ~1) * WREG;     // 2240 floats >= 16*137
    __syncthreads();                          // both halves' conv2 done
    if (rs) {
#pragma unroll
        for (int j = 0; j < 8; ++j) {
            scr[(2 * j) * 137 + lane]           = a2v[j][0].x;
            scr[(2 * j + 1) * 137 + lane]       = a2v[j][0].y;
            scr[(2 * j) * 137 + lane + 64]      = a2v[j][1].x;
            scr[(2 * j + 1) * 137 + lane + 64]  = a2v[j][1].y;
        }
        if (lane < 56) {
            scr[(2 * tj) * 137 + 128 + tt]     = at.x;
            scr[(2 * tj + 1) * 137 + 128 + tt] = at.y;
        }
    }
    __syncthreads();
    if (!rs) {
#pragma unroll
        for (int j = 0; j < 8; ++j) {
            scr[(2 * j) * 137 + lane]           += a2v[j][0].x;
            scr[(2 * j + 1) * 137 + lane]       += a2v[j][0].y;
            scr[(2 * j) * 137 + lane + 64]      += a2v[j][1].x;
            scr[(2 * j + 1) * 137 + lane + 64]  += a2v[j][1].y;
        }
        if (lane < 56) {
            scr[(2 * tj) * 137 + 128 + tt]     += at.x;
            scr[(2 * tj + 1) * 137 + 128 + tt] += at.y;
        }
    }
    __syncthreads();                          // sums visible to both waves

    // ---- top-4 (value desc, tie -> lower t): BOTH waves, 8 lanes per f2 ----
    // 64-bit key = (f2ord(v)<<32) | (0xFFFFFFFF - t); desc == value desc, tie t asc.
    {
        const int f2o = (lane >> 3) + 8 * rs;  // this wave's 8 f2 channels
        const int seg = lane & 7;              // segment of 17 (last has 16)
        const int tstart = seg * 17;
        const float* src = scr + f2o * 137 + tstart;
        const uint32_t tb = 0xFFFFFFFFu - (uint32_t)tstart;
        u64 L0 = 0, L1 = 0, L2 = 0, L3 = 0;    // sentinels (lose to any finite)
#pragma unroll
        for (int i = 0; i < 17; ++i) {
            float v = src[i];                  // seg==7,i==16 reads in-row slack (masked)
            u64 kk = ((u64)f2ord(v) << 32) | (u64)(tb - (uint32_t)i);
            if (i == 16 && seg == 7) kk = 0;
            bool b0 = kk > L0, b1 = kk > L1, b2 = kk > L2, b3 = kk > L3;
            L3 = b3 ? (b2 ? L2 : kk) : L3;
            L2 = b2 ? (b1 ? L1 : kk) : L2;
            L1 = b1 ? (b0 ? L0 : kk) : L1;
            L0 = b0 ? kk : L0;
        }
        // merge 8 segments: 3 shfl rounds; r_i = min_{j+l=i} max(A_j,B_l)
#pragma unroll
        for (int d = 1; d <= 4; d <<= 1) {
            u64 M0 = shflx64(L0, d), M1 = shflx64(L1, d);
            u64 M2 = shflx64(L2, d), M3 = shflx64(L3, d);
            u64 r0 = maxu64(L0, M0);
            u64 r1 = minu64(maxu64(L0, M1), maxu64(L1, M0));
            u64 r2 = minu64(minu64(maxu64(L0, M2), maxu64(L1, M1)), maxu64(L2, M0));
            u64 r3k = minu64(minu64(maxu64(L0, M3), maxu64(L1, M2)),
                             minu64(maxu64(L2, M1), maxu64(L3, M0)));
            L0 = r0; L1 = r1; L2 = r2; L3 = r3k;
        }
        if (seg == 0) {
            // reorder by t ascending == low-32 word descending; emit raw (tanh in FC)
#define CSW2(a, bb) { if ((uint32_t)(bb) > (uint32_t)(a)) { u64 tt2 = (a); (a) = (bb); (bb) = tt2; } }
            CSW2(L0, L1); CSW2(L2, L3); CSW2(L0, L2); CSW2(L1, L3); CSW2(L1, L2);
#undef CSW2
            float* qp = &p2loc[(wv >> 1) * 64 + f2o * 4];
            qp[0] = ord2f((uint32_t)(L0 >> 32));
            qp[1] = ord2f((uint32_t)(L1 >> 32));
            qp[2] = ord2f((uint32_t)(L2 >> 32));
            qp[3] = ord2f((uint32_t)(L3 >> 32));
        }
    }
    __syncthreads();

    // ---- FC partials over 128 features, all 4 waves (3 classes x 64 feats each) ----
    {
        const int nb = (wv >> 1) * 3;          // class base: 0 or 3
        const int fh = (wv & 1) * 64;          // feature half
        float pv = fast_tanh(p2loc[fh + lane]);
#pragma unroll
        for (int i = 0; i < 3; ++i) {
            float s = pv * fcw[(nb + i) * 1024 + q8 * 128 + fh + lane];
#pragma unroll
            for (int off = 32; off > 0; off >>= 1) s += __shfl_xor(s, off, 64);
            if (lane == 0) fred[wv][i] = s;
        }
    }
    __syncthreads();
    if (tid < 6) {
        float v = (tid < 3) ? (fred[0][tid] + fred[1][tid])
                            : (fred[2][tid - 3] + fred[3][tid - 3]);
        atomicAdd(&out[sample * 6 + tid], v);
    }
}

extern "C" void kernel_launch(void* const* d_in, const int* in_sizes, int n_in,
                              void* d_out, int out_size, void* d_ws, size_t ws_size,
                              hipStream_t stream) {
    (void)in_sizes; (void)n_in; (void)out_size; (void)ws_size;
    const int*   x   = (const int*)d_in[0];
    const float* emb = (const float*)d_in[1];
    const float* w1  = (const float*)d_in[2];
    const float* b1  = (const float*)d_in[3];
    const float* w2  = (const float*)d_in[4];
    const float* b2  = (const float*)d_in[5];
    const float* fcw = (const float*)d_in[6];
    const float* fcb = (const float*)d_in[7];
    float* outp = (float*)d_out;
    float* wsf  = (float*)d_ws;   // weights+biases: 24576 floats

    dcnn_prep<<<96, 256, 0, stream>>>(w1, b1, w2, b2, fcb, outp, wsf);
    dcnn_main<<<4096, 256, 0, stream>>>(x, emb, fcw, wsf, outp);
}

// Round 6
// 196.239 us; speedup vs baseline: 1.0664x; 1.0487x over previous
//
#include <hip/hip_runtime.h>
#include <stdint.h>

// ---------------- problem constants ----------------
#define S_LEN 256
#define OUT1  262      // S + 7 - 1
#define K1SEL 131      // ceil((2-1)/2 * 262)
#define OUT2  135      // 131 + 5 - 1
// ws layout (floats)
#define W1T_OFF 0          // w1t[d][k][f]      64*7*8   = 3584
#define W2T_OFF 3584       // w2t[g][ic][k][f2] 32*8*5*16= 20480
#define B1C_OFF 24064      // b1c[r2][f]        32*8
#define B2C_OFF 24320      // b2c[r3][f2]       16*16
#define WREG    1120       // floats per wave LDS region

typedef float v2f __attribute__((ext_vector_type(2)));
__device__ __forceinline__ v2f fma2(v2f a, v2f b, v2f c) {
    return __builtin_elementwise_fma(a, b, c);   // -> v_pk_fma_f32 (exact fma/lane)
}

__device__ __forceinline__ int lane_prefix(unsigned long long m) {
    return __builtin_amdgcn_mbcnt_hi((uint32_t)(m >> 32),
           __builtin_amdgcn_mbcnt_lo((uint32_t)m, 0));
}
__device__ __forceinline__ uint32_t f2ord(float x) {
    uint32_t b = __float_as_uint(x);
    return (b & 0x80000000u) ? ~b : (b | 0x80000000u);
}
__device__ __forceinline__ float ord2f(uint32_t s) {
    uint32_t b = (s & 0x80000000u) ? (s & 0x7FFFFFFFu) : ~s;
    return __uint_as_float(b);
}
// tanh via hw rcp: (e-1)*rcp(e+1), e=exp(2x). applied strictly AFTER selection.
__device__ __forceinline__ float fast_tanh(float x) {
    float e = __expf(2.0f * x);
    return (e - 1.0f) * __builtin_amdgcn_rcpf(e + 1.0f);
}
typedef unsigned long long u64;
__device__ __forceinline__ u64 shflx64(u64 v, int m) {
    uint32_t lo = (uint32_t)__shfl_xor((int)(uint32_t)v, m, 64);
    uint32_t hi = (uint32_t)__shfl_xor((int)(uint32_t)(v >> 32), m, 64);
    return ((u64)hi << 32) | lo;
}
__device__ __forceinline__ u64 maxu64(u64 a, u64 b) { return a > b ? a : b; }
__device__ __forceinline__ u64 minu64(u64 a, u64 b) { return a < b ? a : b; }
// sorted-desc top-4 bubble insert: 3 (max,min) pairs + final max.
// each pair shares one v_cmp_lt_u64 (same vcc for both cndmask pairs).
__device__ __forceinline__ void ins4(u64 kk, u64 &L0, u64 &L1, u64 &L2, u64 &L3) {
    u64 a0 = maxu64(L0, kk), s0 = minu64(L0, kk); L0 = a0;
    u64 a1 = maxu64(L1, s0), s1 = minu64(L1, s0); L1 = a1;
    u64 a2 = maxu64(L2, s1), s2 = minu64(L2, s1); L2 = a2;
    L3 = maxu64(L3, s2);
}

// ------------- prep: transpose weights / fold biases into ws; init out with bias -------------
extern "C" __global__ void dcnn_prep(const float* __restrict__ w1, const float* __restrict__ b1,
                                     const float* __restrict__ w2, const float* __restrict__ b2,
                                     const float* __restrict__ fcb, float* __restrict__ out,
                                     float* __restrict__ ws) {
    int i = blockIdx.x * 256 + threadIdx.x;   // 96*256 == 24576
    if (i < 3072) out[i] = fcb[i % 6];        // out[s*6+n] = fcb[n]
    if (i < W2T_OFF) {                        // w1t[d][k][f] = w1[(d*8+f)*7 + k]
        int d = i / 56, r = i % 56, k = r / 8, f = r % 8;
        ws[i] = w1[(d * 8 + f) * 7 + k];
    } else if (i < B1C_OFF) {                 // w2t[g][ic][k][f2] = w2[((g*16+f2)*8+ic)*5+k]
        int q = i - W2T_OFF;
        int g = q / 640, r = q % 640;
        int ic = r / 80, r2 = r % 80;
        int k = r2 / 16, f2 = r2 % 16;
        ws[i] = w2[((g * 16 + f2) * 8 + ic) * 5 + k];
    } else if (i < B2C_OFF) {                 // b1c[r2][f] = b1[2r2*8+f] + b1[(2r2+1)*8+f]
        int q = i - B1C_OFF;
        int r2 = q / 8, f = q % 8;
        ws[i] = b1[(2 * r2) * 8 + f] + b1[(2 * r2 + 1) * 8 + f];
    } else {                                  // b2c[r3][f2]
        int q = i - B2C_OFF;
        int r3 = q / 16, f2 = q % 16;
        ws[i] = b2[(2 * r3) * 16 + f2] + b2[(2 * r3 + 1) * 16 + f2];
    }
}

// ------------- main: one wave = one (slice, rs-half) task; R19 structure -------------
// Block = 256 thr (4 waves) = 2 slices x 2 rs-halves of ONE sample; grid 4096.
// R19 = EXACT R16 chassis (134.6us, VGPR 32, occ 70%) + liveness-neutral diet:
// (a) compaction writes raw ORDINAL bits; ord2f fused into dense tanh pass
// (guards = -0.0f = ord(0.0)). (b) top-4 insert = min/max bubble cascade
// (shared-vcc pairs, ~18 vs ~32 VALU/iter, same 8 live u64). (c) top-4 loop:
// 16 clean iters (#pragma unroll 1 -- R18's full unroll hoisted 17 loads,
// VGPR 32->64, occ 40%, REVERTED) + one masked 17th step outside.
// xs LDS staging KEPT (R18 removed it as part of the VGPR-bloat bundle).
// R17 lesson: conv2 t-split blew VGPR -> occupancy x issue-density rules.
// R16: conv2 m=2 chunk -> 56-lane per-lane tail; radix 16-bit fused 8-ch;
// FC over 4 waves. R14: no-refine <=> count(u>=pre)==K via ge. R13: 128thr
// blocks regressed. R12: rcp-tanh dense post-pass. R11: v_pk_fma_f32.
// R9: waves_per_eu(4,8). R3: all acc/u indices compile-time.
extern "C" __global__
__attribute__((amdgpu_flat_work_group_size(256, 256), amdgpu_waves_per_eu(4, 8)))
void dcnn_main(const int* __restrict__ x, const float* __restrict__ emb,
               const float* __restrict__ fcw, const float* __restrict__ ws,
               float* __restrict__ out) {
    __shared__ float uni[4 * WREG];       // 17920 B
    __shared__ int   xs[S_LEN];           // 1 KB
    __shared__ float p2loc[128];          // this block's 128 FC features (raw, pre-tanh)
    __shared__ float fred[4][3];

    const int tid    = threadIdx.x;
    const int lane   = tid & 63;
    const int wv     = __builtin_amdgcn_readfirstlane(tid >> 6);  // 0..3
    const int sample = blockIdx.x >> 3;
    const int q8     = blockIdx.x & 7;
    const int sl     = q8 * 2 + (wv >> 1);   // global slice r3 in [0,16)
    const int rs     = wv & 1;               // which half of the fold pair

    const float* w1t = ws + W1T_OFF;
    const float* w2t = ws + W2T_OFF;
    const float* b1c = ws + B1C_OFF;
    const float* b2c = ws + B2C_OFF;

    xs[tid] = x[sample * S_LEN + tid];
    __syncthreads();

    float*  reg   = uni + wv * WREG;
    float2* rowsW = (float2*)reg;          // 272 float2 = 544 floats
    float*  p1w   = reg;                   // [f:8][140]

    // ---- guards + stage 2 embedding rows (d = 4sl+2rs, +1) as float2 per j ----
    if (lane < 8) {
        rowsW[lane]       = make_float2(0.f, 0.f);
        rowsW[264 + lane] = make_float2(0.f, 0.f);
    }
    const int dbase = 4 * sl + 2 * rs;
#pragma unroll
    for (int m = 0; m < 4; ++m) {
        int j  = lane + 64 * m;            // input pos 0..255
        int xi = xs[j];
        rowsW[8 + j] = *(const float2*)(emb + (size_t)xi * 64 + dbase);
    }

    // ---- conv1 (K=7, depthwise) + fold: 8 channels as 4 packed pairs ----
    v2f acc2[4][5];
#pragma unroll
    for (int j = 0; j < 4; ++j) {
        v2f bz = *(const v2f*)(b1c + (2 * sl + rs) * 8 + 2 * j);
#pragma unroll
        for (int m = 0; m < 5; ++m) acc2[j][m] = bz;
    }
    int tA[5];
#pragma unroll
    for (int m = 0; m < 5; ++m) { int t = lane + 64 * m; tA[m] = (t < OUT1) ? t : (OUT1 - 1); }

#pragma unroll 1
    for (int k = 0; k < 7; ++k) {
        v2f wa[4], wb[4];
#pragma unroll
        for (int j = 0; j < 4; ++j) {
            wa[j] = *(const v2f*)(w1t + (dbase * 7 + k) * 8 + 2 * j);
            wb[j] = *(const v2f*)(w1t + ((dbase + 1) * 7 + k) * 8 + 2 * j);
        }
#pragma unroll
        for (int m = 0; m < 5; ++m) {
            float2 v = rowsW[tA[m] + 2 + k];   // j = t-6+k, +8 guard offset
            v2f vx = { v.x, v.x };
            v2f vy = { v.y, v.y };
#pragma unroll
            for (int j = 0; j < 4; ++j) {
                acc2[j][m] = fma2(wa[j], vx, acc2[j][m]);
                acc2[j][m] = fma2(wb[j], vy, acc2[j][m]);
            }
        }
    }

    // ---- p1 guards (rows region dead; p1 aliases it). 64 lanes = 8 ch x 8 slots ----
    // guard value = -0.0f == bits of ord(0.0): tanh pass ord2f's it back to +0.
    {
        int c = lane >> 3, j = lane & 7;
        int pos = (j < 4) ? j : (131 + j);
        p1w[c * 140 + pos] = __uint_as_float(0x80000000u);
    }

    // ---- exact order-preserving top-131 per channel (fused 16-bit radix) ----
    uint32_t uu[4][2][5];
#pragma unroll
    for (int cp = 0; cp < 4; ++cp) {
#pragma unroll
        for (int m = 0; m < 4; ++m) {          // t = lane+64m < 256 < OUT1 always
            uu[cp][0][m] = f2ord(acc2[cp][m].x);
            uu[cp][1][m] = f2ord(acc2[cp][m].y);
        }
        uu[cp][0][4] = (lane < 6) ? f2ord(acc2[cp][4].x) : 0u;   // t=lane+256 < 262
        uu[cp][1][4] = (lane < 6) ? f2ord(acc2[cp][4].y) : 0u;
    }
    uint32_t pre[8];
    int ge[8];                                 // count(u>=pre) at last accept
#pragma unroll
    for (int c = 0; c < 8; ++c) { pre[c] = 0u; ge[c] = 0x7FFFFFFF; }
#pragma unroll 1
    for (int bit = 31; bit >= 16; --bit) {
#pragma unroll
        for (int c = 0; c < 8; ++c) {
            uint32_t cand = pre[c] | (1u << bit);
            int n = 0;
#pragma unroll
            for (int m = 0; m < 5; ++m)
                n += __popcll(__ballot(uu[c >> 1][c & 1][m] >= cand));
            if (n >= K1SEL) { pre[c] = cand; ge[c] = n; }
        }
    }
    // ---- per-pair compaction: writes ORDINAL bits (ord2f+tanh later) ----
#pragma unroll
    for (int cp = 0; cp < 4; ++cp) {
        uint32_t preA = pre[2 * cp], preB = pre[2 * cp + 1];
        float* dstA = p1w + (2 * cp) * 140 + 4;
        float* dstB = p1w + (2 * cp + 1) * 140 + 4;
        if (ge[2 * cp] == K1SEL && ge[2 * cp + 1] == K1SEL) {
            // common path: class boundary exact -> keep = (u >= pre), all ties kept
            int kpA = 0, kpB = 0;
#pragma unroll
            for (int m = 0; m < 5; ++m) {
                unsigned long long kmA = __ballot(uu[cp][0][m] >= preA);
                unsigned long long kmB = __ballot(uu[cp][1][m] >= preB);
                int posA = kpA + lane_prefix(kmA);     // order-preserving compaction
                int posB = kpB + lane_prefix(kmB);
                if (uu[cp][0][m] >= preA) dstA[posA] = __uint_as_float(uu[cp][0][m]);
                if (uu[cp][1][m] >= preB) dstB[posB] = __uint_as_float(uu[cp][1][m]);
                kpA += __popcll(kmA); kpB += __popcll(kmB);
            }
        } else {
            // rare path: boundary inside a 16-bit class -> refine low bits fully
#pragma unroll 1
            for (int bit = 15; bit >= 0; --bit) {
                uint32_t cA = preA | (1u << bit);
                uint32_t cB = preB | (1u << bit);
                int na = 0, nb = 0;
#pragma unroll
                for (int m = 0; m < 5; ++m) {
                    na += __popcll(__ballot(uu[cp][0][m] >= cA));
                    nb += __popcll(__ballot(uu[cp][1][m] >= cB));
                }
                if (na >= K1SEL) preA = cA;
                if (nb >= K1SEL) preB = cB;
            }
            int cgtA = 0, cgtB = 0;
#pragma unroll
            for (int m = 0; m < 5; ++m) {
                cgtA += __popcll(__ballot(uu[cp][0][m] > preA));
                cgtB += __popcll(__ballot(uu[cp][1][m] > preB));
            }
            const int needA = K1SEL - cgtA;            // #ties kept (earliest t first)
            const int needB = K1SEL - cgtB;
            int eqA = 0, kpA = 0, eqB = 0, kpB = 0;
#pragma unroll
            for (int m = 0; m < 5; ++m) {
                unsigned long long emA = __ballot(uu[cp][0][m] == preA);
                unsigned long long emB = __ballot(uu[cp][1][m] == preB);
                int erA = eqA + lane_prefix(emA);
                int erB = eqB + lane_prefix(emB);
                bool keepA = (uu[cp][0][m] > preA) || ((uu[cp][0][m] == preA) && (erA < needA));
                bool keepB = (uu[cp][1][m] > preB) || ((uu[cp][1][m] == preB) && (erB < needB));
                unsigned long long kmA = __ballot(keepA);
                unsigned long long kmB = __ballot(keepB);
                int posA = kpA + lane_prefix(kmA);
                int posB = kpB + lane_prefix(kmB);
                if (keepA) dstA[posA] = __uint_as_float(uu[cp][0][m]);
                if (keepB) dstB[posB] = __uint_as_float(uu[cp][1][m]);
                eqA += __popcll(emA); kpA += __popcll(kmA);
                eqB += __popcll(emB); kpB += __popcll(kmB);
            }
        }
    }

    // ---- dense ord2f+tanh post-pass over the whole p1 region (1120 floats) ----
    // guards are ord(0)->0; slot 139 holds garbage, only read by inactive
    // tail lanes (tt==7, lane>=56 -> result unused).
#pragma unroll
    for (int i = 0; i < 17; ++i) {
        int idx = lane + 64 * i;
        p1w[idx] = fast_tanh(ord2f(__float_as_uint(p1w[idx])));
    }
    if (lane < 32) {
        int idx = lane + 64 * 17;
        p1w[idx] = fast_tanh(ord2f(__float_as_uint(p1w[idx])));
    }

    // ---- conv2 partial: group g = 2sl+rs; 16 f2 as 8 packed pairs ----
    // main chunks m=0,1 (t=0..127, all lanes useful); t=128..134 via per-lane tail.
    const int g = 2 * sl + rs;
    const v2f* b2v = (const v2f*)(b2c + sl * 16);
    v2f a2v[8][2];
#pragma unroll
    for (int j = 0; j < 8; ++j) {
        v2f bz = rs ? (v2f){0.f, 0.f} : b2v[j];   // pre-folded bias counted once
        a2v[j][0] = bz; a2v[j][1] = bz;
    }

#pragma unroll 1
    for (int ic = 0; ic < 8; ++ic) {
        const float* src = p1w + ic * 140;   // logical t' = idx - 4
        float win[2][5];                     // straight-line, all offsets compile-time
#pragma unroll
        for (int m = 0; m < 2; ++m) {
#pragma unroll
            for (int k = 0; k < 5; ++k) win[m][k] = src[lane + 64 * m + k];
        }
#pragma unroll
        for (int k = 0; k < 5; ++k) {
            const v2f* wv2 = (const v2f*)(w2t + ((g * 8 + ic) * 5 + k) * 16);
            v2f s0 = { win[0][k], win[0][k] };
            v2f s1 = { win[1][k], win[1][k] };
#pragma unroll
            for (int j = 0; j < 8; ++j) {
                v2f w = wv2[j];
                a2v[j][0] = fma2(w, s0, a2v[j][0]);
                a2v[j][1] = fma2(w, s1, a2v[j][1]);
            }
        }
    }

    // per-lane tail: lanes 0..55 each own (t = 128+tt, f2-pair tj)
    const int tt = lane >> 3;                // 0..7 (7 = inactive)
    const int tj = lane & 7;
    v2f at = (!rs) ? b2v[tj] : (v2f){0.f, 0.f};
    {
        const float* tsrc0 = p1w + 128 + tt;             // + ic*140 + k (imm)
        const float* tw    = w2t + g * 640 + 2 * tj;     // + (ic*5+k)*16 (imm)
#pragma unroll
        for (int ic = 0; ic < 8; ++ic) {
#pragma unroll
            for (int k = 0; k < 5; ++k) {
                float sv = tsrc0[ic * 140 + k];          // <=139: in-region even for tt=7
                v2f w = *(const v2f*)(tw + (ic * 5 + k) * 16);
                v2f sb = { sv, sv };
                at = fma2(w, sb, at);
            }
        }
    }

    // ---- cross-wave fold (a2 sum) in the pair's dead p1 regions ----
    float* scr = uni + (wv & ~1) * WREG;     // 2240 floats >= 16*137
    __syncthreads();                          // both halves' conv2 done
    if (rs) {
#pragma unroll
        for (int j = 0; j < 8; ++j) {
            scr[(2 * j) * 137 + lane]           = a2v[j][0].x;
            scr[(2 * j + 1) * 137 + lane]       = a2v[j][0].y;
            scr[(2 * j) * 137 + lane + 64]      = a2v[j][1].x;
            scr[(2 * j + 1) * 137 + lane + 64]  = a2v[j][1].y;
        }
        if (lane < 56) {
            scr[(2 * tj) * 137 + 128 + tt]     = at.x;
            scr[(2 * tj + 1) * 137 + 128 + tt] = at.y;
        }
    }
    __syncthreads();
    if (!rs) {
#pragma unroll
        for (int j = 0; j < 8; ++j) {
            scr[(2 * j) * 137 + lane]           += a2v[j][0].x;
            scr[(2 * j + 1) * 137 + lane]       += a2v[j][0].y;
            scr[(2 * j) * 137 + lane + 64]      += a2v[j][1].x;
            scr[(2 * j + 1) * 137 + lane + 64]  += a2v[j][1].y;
        }
        if (lane < 56) {
            scr[(2 * tj) * 137 + 128 + tt]     += at.x;
            scr[(2 * tj + 1) * 137 + 128 + tt] += at.y;
        }
    }
    __syncthreads();                          // sums visible to both waves

    // ---- top-4 (value desc, tie -> lower t): BOTH waves, 8 lanes per f2 ----
    // 64-bit key = (f2ord(v)<<32) | (0xFFFFFFFF - t); desc == value desc, tie t asc.
    {
        const int f2o = (lane >> 3) + 8 * rs;  // this wave's 8 f2 channels
        const int seg = lane & 7;              // segment of 17 (last has 16)
        const int tstart = seg * 17;
        const float* src = scr + f2o * 137 + tstart;
        const uint32_t tb = 0xFFFFFFFFu - (uint32_t)tstart;
        u64 L0 = 0, L1 = 0, L2 = 0, L3 = 0;    // sentinels (lose to any finite)
#pragma unroll 1
        for (int i = 0; i < 16; ++i) {         // always-valid iters, no clamp
            u64 kk = ((u64)f2ord(src[i]) << 32) | (u64)(tb - (uint32_t)i);
            ins4(kk, L0, L1, L2, L3);
        }
        {                                      // 17th elem: invalid only for seg==7
            u64 kk = ((u64)f2ord(src[16]) << 32) | (u64)(tb - 16u);
            if (seg == 7) kk = 0;              // index 135 = row slack, masked
            ins4(kk, L0, L1, L2, L3);
        }
        // merge 8 segments: 3 shfl rounds; r_i = min_{j+l=i} max(A_j,B_l)
#pragma unroll
        for (int d = 1; d <= 4; d <<= 1) {
            u64 M0 = shflx64(L0, d), M1 = shflx64(L1, d);
            u64 M2 = shflx64(L2, d), M3 = shflx64(L3, d);
            u64 r0 = maxu64(L0, M0);
            u64 r1 = minu64(maxu64(L0, M1), maxu64(L1, M0));
            u64 r2 = minu64(minu64(maxu64(L0, M2), maxu64(L1, M1)), maxu64(L2, M0));
            u64 r3k = minu64(minu64(maxu64(L0, M3), maxu64(L1, M2)),
                             minu64(maxu64(L2, M1), maxu64(L3, M0)));
            L0 = r0; L1 = r1; L2 = r2; L3 = r3k;
        }
        if (seg == 0) {
            // reorder by t ascending == low-32 word descending; emit raw (tanh in FC)
#define CSW2(a, bb) { if ((uint32_t)(bb) > (uint32_t)(a)) { u64 tt2 = (a); (a) = (bb); (bb) = tt2; } }
            CSW2(L0, L1); CSW2(L2, L3); CSW2(L0, L2); CSW2(L1, L3); CSW2(L1, L2);
#undef CSW2
            float* qp = &p2loc[(wv >> 1) * 64 + f2o * 4];
            qp[0] = ord2f((uint32_t)(L0 >> 32));
            qp[1] = ord2f((uint32_t)(L1 >> 32));
            qp[2] = ord2f((uint32_t)(L2 >> 32));
            qp[3] = ord2f((uint32_t)(L3 >> 32));
        }
    }
    __syncthreads();

    // ---- FC partials over 128 features, all 4 waves (3 classes x 64 feats each) ----
    {
        const int nb = (wv >> 1) * 3;          // class base: 0 or 3
        const int fh = (wv & 1) * 64;          // feature half
        float pv = fast_tanh(p2loc[fh + lane]);
#pragma unroll
        for (int i = 0; i < 3; ++i) {
            float s = pv * fcw[(nb + i) * 1024 + q8 * 128 + fh + lane];
#pragma unroll
            for (int off = 32; off > 0; off >>= 1) s += __shfl_xor(s, off, 64);
            if (lane == 0) fred[wv][i] = s;
        }
    }
    __syncthreads();
    if (tid < 6) {
        float v = (tid < 3) ? (fred[0][tid] + fred[1][tid])
                            : (fred[2][tid - 3] + fred[3][tid - 3]);
        atomicAdd(&out[sample * 6 + tid], v);
    }
}

extern "C" void kernel_launch(void* const* d_in, const int* in_sizes, int n_in,
                              void* d_out, int out_size, void* d_ws, size_t ws_size,
                              hipStream_t stream) {
    (void)in_sizes; (void)n_in; (void)out_size; (void)ws_size;
    const int*   x   = (const int*)d_in[0];
    const float* emb = (const float*)d_in[1];
    const float* w1  = (const float*)d_in[2];
    const float* b1  = (const float*)d_in[3];
    const float* w2  = (const float*)d_in[4];
    const float* b2  = (const float*)d_in[5];
    const float* fcw = (const float*)d_in[6];
    const float* fcb = (const float*)d_in[7];
    float* outp = (float*)d_out;
    float* wsf  = (float*)d_ws;   // weights+biases: 24576 floats

    dcnn_prep<<<96, 256, 0, stream>>>(w1, b1, w2, b2, fcb, outp, wsf);
    dcnn_main<<<4096, 256, 0, stream>>>(x, emb, fcw, wsf, outp);
}

// Round 7
// 188.638 us; speedup vs baseline: 1.1094x; 1.0403x over previous
//
#include <hip/hip_runtime.h>
#include <stdint.h>

// ---------------- problem constants ----------------
#define S_LEN 256
#define OUT1  262      // S + 7 - 1
#define K1SEL 131      // ceil((2-1)/2 * 262)
#define OUT2  135      // 131 + 5 - 1
// ws layout (floats)
#define W1T_OFF 0          // w1t[d][k][f]      64*7*8   = 3584
#define W2T_OFF 3584       // w2t[g][ic][k][f2] 32*8*5*16= 20480
#define B1C_OFF 24064      // b1c[r2][f]        32*8
#define B2C_OFF 24320      // b2c[r3][f2]       16*16
#define WREG    1120       // floats per wave LDS region

typedef float v2f __attribute__((ext_vector_type(2)));
__device__ __forceinline__ v2f fma2(v2f a, v2f b, v2f c) {
    return __builtin_elementwise_fma(a, b, c);   // -> v_pk_fma_f32 (exact fma/lane)
}

__device__ __forceinline__ int lane_prefix(unsigned long long m) {
    return __builtin_amdgcn_mbcnt_hi((uint32_t)(m >> 32),
           __builtin_amdgcn_mbcnt_lo((uint32_t)m, 0));
}
__device__ __forceinline__ uint32_t f2ord(float x) {
    uint32_t b = __float_as_uint(x);
    return (b & 0x80000000u) ? ~b : (b | 0x80000000u);
}
__device__ __forceinline__ float ord2f(uint32_t s) {
    uint32_t b = (s & 0x80000000u) ? (s & 0x7FFFFFFFu) : ~s;
    return __uint_as_float(b);
}
// tanh via hw rcp: (e-1)*rcp(e+1), e=exp(2x). applied strictly AFTER selection.
__device__ __forceinline__ float fast_tanh(float x) {
    float e = __expf(2.0f * x);
    return (e - 1.0f) * __builtin_amdgcn_rcpf(e + 1.0f);
}

// ------------- prep: transpose weights / fold biases into ws; init out with bias -------------
extern "C" __global__ void dcnn_prep(const float* __restrict__ w1, const float* __restrict__ b1,
                                     const float* __restrict__ w2, const float* __restrict__ b2,
                                     const float* __restrict__ fcb, float* __restrict__ out,
                                     float* __restrict__ ws) {
    int i = blockIdx.x * 256 + threadIdx.x;   // 96*256 == 24576
    if (i < 3072) out[i] = fcb[i % 6];        // out[s*6+n] = fcb[n]
    if (i < W2T_OFF) {                        // w1t[d][k][f] = w1[(d*8+f)*7 + k]
        int d = i / 56, r = i % 56, k = r / 8, f = r % 8;
        ws[i] = w1[(d * 8 + f) * 7 + k];
    } else if (i < B1C_OFF) {                 // w2t[g][ic][k][f2] = w2[((g*16+f2)*8+ic)*5+k]
        int q = i - W2T_OFF;
        int g = q / 640, r = q % 640;
        int ic = r / 80, r2 = r % 80;
        int k = r2 / 16, f2 = r2 % 16;
        ws[i] = w2[((g * 16 + f2) * 8 + ic) * 5 + k];
    } else if (i < B2C_OFF) {                 // b1c[r2][f] = b1[2r2*8+f] + b1[(2r2+1)*8+f]
        int q = i - B1C_OFF;
        int r2 = q / 8, f = q % 8;
        ws[i] = b1[(2 * r2) * 8 + f] + b1[(2 * r2 + 1) * 8 + f];
    } else {                                  // b2c[r3][f2]
        int q = i - B2C_OFF;
        int r3 = q / 16, f2 = q % 16;
        ws[i] = b2[(2 * r3) * 16 + f2] + b2[(2 * r3 + 1) * 16 + f2];
    }
}

// ------------- main: one wave = one (slice, rs-half) task; R20 structure -------------
// Block = 256 thr (4 waves) = 2 slices x 2 rs-halves of ONE sample; grid 4096.
// R20 = R19 chassis (129us, VGPR 32, occ 69%) + FLOAT top-4 (replaces u64-key
// machinery, ~650 VALU -> ~330): pass1 = v_max/min_f32 bubble top-4 (7 i/elem
// vs 23) + float butterfly merge (16 i/round vs 80, 32-bit shfl); pass2 =
// thr=L3, per-lane gt/eq counts, ONE packed shfl_up prefix over the 8-seg
// group, ordered re-scan emits kept elems directly at their t-rank slot (CSW
// sort gone). Tie semantics = earliest-t, identical to u64 keys (jax top_k
// stable); +-0 merge is FC-neutral (both contribute 0). All loops stay
// #pragma unroll 1 (R18: full unroll -> VGPR 64, occ 40%, REVERTED).
// R19: ordinal-bit compaction + ord2f-in-tanh; bubble insert. R17 lesson:
// conv2 t-split blew VGPR -> occupancy x issue-density rules. R16: conv2
// per-lane tail; radix 16-bit fused 8-ch; FC over 4 waves. R14: no-refine <=>
// count(u>=pre)==K via ge. R12: rcp-tanh dense post-pass. R11: v_pk_fma_f32.
// R9: waves_per_eu(4,8). R3: all acc/u indices compile-time.
extern "C" __global__
__attribute__((amdgpu_flat_work_group_size(256, 256), amdgpu_waves_per_eu(4, 8)))
void dcnn_main(const int* __restrict__ x, const float* __restrict__ emb,
               const float* __restrict__ fcw, const float* __restrict__ ws,
               float* __restrict__ out) {
    __shared__ float uni[4 * WREG];       // 17920 B
    __shared__ int   xs[S_LEN];           // 1 KB
    __shared__ float p2loc[128];          // this block's 128 FC features (raw, pre-tanh)
    __shared__ float fred[4][3];

    const int tid    = threadIdx.x;
    const int lane   = tid & 63;
    const int wv     = __builtin_amdgcn_readfirstlane(tid >> 6);  // 0..3
    const int sample = blockIdx.x >> 3;
    const int q8     = blockIdx.x & 7;
    const int sl     = q8 * 2 + (wv >> 1);   // global slice r3 in [0,16)
    const int rs     = wv & 1;               // which half of the fold pair

    const float* w1t = ws + W1T_OFF;
    const float* w2t = ws + W2T_OFF;
    const float* b1c = ws + B1C_OFF;
    const float* b2c = ws + B2C_OFF;

    xs[tid] = x[sample * S_LEN + tid];
    __syncthreads();

    float*  reg   = uni + wv * WREG;
    float2* rowsW = (float2*)reg;          // 272 float2 = 544 floats
    float*  p1w   = reg;                   // [f:8][140]

    // ---- guards + stage 2 embedding rows (d = 4sl+2rs, +1) as float2 per j ----
    if (lane < 8) {
        rowsW[lane]       = make_float2(0.f, 0.f);
        rowsW[264 + lane] = make_float2(0.f, 0.f);
    }
    const int dbase = 4 * sl + 2 * rs;
#pragma unroll
    for (int m = 0; m < 4; ++m) {
        int j  = lane + 64 * m;            // input pos 0..255
        int xi = xs[j];
        rowsW[8 + j] = *(const float2*)(emb + (size_t)xi * 64 + dbase);
    }

    // ---- conv1 (K=7, depthwise) + fold: 8 channels as 4 packed pairs ----
    v2f acc2[4][5];
#pragma unroll
    for (int j = 0; j < 4; ++j) {
        v2f bz = *(const v2f*)(b1c + (2 * sl + rs) * 8 + 2 * j);
#pragma unroll
        for (int m = 0; m < 5; ++m) acc2[j][m] = bz;
    }
    int tA[5];
#pragma unroll
    for (int m = 0; m < 5; ++m) { int t = lane + 64 * m; tA[m] = (t < OUT1) ? t : (OUT1 - 1); }

#pragma unroll 1
    for (int k = 0; k < 7; ++k) {
        v2f wa[4], wb[4];
#pragma unroll
        for (int j = 0; j < 4; ++j) {
            wa[j] = *(const v2f*)(w1t + (dbase * 7 + k) * 8 + 2 * j);
            wb[j] = *(const v2f*)(w1t + ((dbase + 1) * 7 + k) * 8 + 2 * j);
        }
#pragma unroll
        for (int m = 0; m < 5; ++m) {
            float2 v = rowsW[tA[m] + 2 + k];   // j = t-6+k, +8 guard offset
            v2f vx = { v.x, v.x };
            v2f vy = { v.y, v.y };
#pragma unroll
            for (int j = 0; j < 4; ++j) {
                acc2[j][m] = fma2(wa[j], vx, acc2[j][m]);
                acc2[j][m] = fma2(wb[j], vy, acc2[j][m]);
            }
        }
    }

    // ---- p1 guards (rows region dead; p1 aliases it). 64 lanes = 8 ch x 8 slots ----
    // guard value = -0.0f == bits of ord(0.0): tanh pass ord2f's it back to +0.
    {
        int c = lane >> 3, j = lane & 7;
        int pos = (j < 4) ? j : (131 + j);
        p1w[c * 140 + pos] = __uint_as_float(0x80000000u);
    }

    // ---- exact order-preserving top-131 per channel (fused 16-bit radix) ----
    uint32_t uu[4][2][5];
#pragma unroll
    for (int cp = 0; cp < 4; ++cp) {
#pragma unroll
        for (int m = 0; m < 4; ++m) {          // t = lane+64m < 256 < OUT1 always
            uu[cp][0][m] = f2ord(acc2[cp][m].x);
            uu[cp][1][m] = f2ord(acc2[cp][m].y);
        }
        uu[cp][0][4] = (lane < 6) ? f2ord(acc2[cp][4].x) : 0u;   // t=lane+256 < 262
        uu[cp][1][4] = (lane < 6) ? f2ord(acc2[cp][4].y) : 0u;
    }
    uint32_t pre[8];
    int ge[8];                                 // count(u>=pre) at last accept
#pragma unroll
    for (int c = 0; c < 8; ++c) { pre[c] = 0u; ge[c] = 0x7FFFFFFF; }
#pragma unroll 1
    for (int bit = 31; bit >= 16; --bit) {
#pragma unroll
        for (int c = 0; c < 8; ++c) {
            uint32_t cand = pre[c] | (1u << bit);
            int n = 0;
#pragma unroll
            for (int m = 0; m < 5; ++m)
                n += __popcll(__ballot(uu[c >> 1][c & 1][m] >= cand));
            if (n >= K1SEL) { pre[c] = cand; ge[c] = n; }
        }
    }
    // ---- per-pair compaction: writes ORDINAL bits (ord2f+tanh later) ----
#pragma unroll
    for (int cp = 0; cp < 4; ++cp) {
        uint32_t preA = pre[2 * cp], preB = pre[2 * cp + 1];
        float* dstA = p1w + (2 * cp) * 140 + 4;
        float* dstB = p1w + (2 * cp + 1) * 140 + 4;
        if (ge[2 * cp] == K1SEL && ge[2 * cp + 1] == K1SEL) {
            // common path: class boundary exact -> keep = (u >= pre), all ties kept
            int kpA = 0, kpB = 0;
#pragma unroll
            for (int m = 0; m < 5; ++m) {
                unsigned long long kmA = __ballot(uu[cp][0][m] >= preA);
                unsigned long long kmB = __ballot(uu[cp][1][m] >= preB);
                int posA = kpA + lane_prefix(kmA);     // order-preserving compaction
                int posB = kpB + lane_prefix(kmB);
                if (uu[cp][0][m] >= preA) dstA[posA] = __uint_as_float(uu[cp][0][m]);
                if (uu[cp][1][m] >= preB) dstB[posB] = __uint_as_float(uu[cp][1][m]);
                kpA += __popcll(kmA); kpB += __popcll(kmB);
            }
        } else {
            // rare path: boundary inside a 16-bit class -> refine low bits fully
#pragma unroll 1
            for (int bit = 15; bit >= 0; --bit) {
                uint32_t cA = preA | (1u << bit);
                uint32_t cB = preB | (1u << bit);
                int na = 0, nb = 0;
#pragma unroll
                for (int m = 0; m < 5; ++m) {
                    na += __popcll(__ballot(uu[cp][0][m] >= cA));
                    nb += __popcll(__ballot(uu[cp][1][m] >= cB));
                }
                if (na >= K1SEL) preA = cA;
                if (nb >= K1SEL) preB = cB;
            }
            int cgtA = 0, cgtB = 0;
#pragma unroll
            for (int m = 0; m < 5; ++m) {
                cgtA += __popcll(__ballot(uu[cp][0][m] > preA));
                cgtB += __popcll(__ballot(uu[cp][1][m] > preB));
            }
            const int needA = K1SEL - cgtA;            // #ties kept (earliest t first)
            const int needB = K1SEL - cgtB;
            int eqA = 0, kpA = 0, eqB = 0, kpB = 0;
#pragma unroll
            for (int m = 0; m < 5; ++m) {
                unsigned long long emA = __ballot(uu[cp][0][m] == preA);
                unsigned long long emB = __ballot(uu[cp][1][m] == preB);
                int erA = eqA + lane_prefix(emA);
                int erB = eqB + lane_prefix(emB);
                bool keepA = (uu[cp][0][m] > preA) || ((uu[cp][0][m] == preA) && (erA < needA));
                bool keepB = (uu[cp][1][m] > preB) || ((uu[cp][1][m] == preB) && (erB < needB));
                unsigned long long kmA = __ballot(keepA);
                unsigned long long kmB = __ballot(keepB);
                int posA = kpA + lane_prefix(kmA);
                int posB = kpB + lane_prefix(kmB);
                if (keepA) dstA[posA] = __uint_as_float(uu[cp][0][m]);
                if (keepB) dstB[posB] = __uint_as_float(uu[cp][1][m]);
                eqA += __popcll(emA); kpA += __popcll(kmA);
                eqB += __popcll(emB); kpB += __popcll(kmB);
            }
        }
    }

    // ---- dense ord2f+tanh post-pass over the whole p1 region (1120 floats) ----
    // guards are ord(0)->0; slot 139 holds garbage, only read by inactive
    // tail lanes (tt==7, lane>=56 -> result unused).
#pragma unroll
    for (int i = 0; i < 17; ++i) {
        int idx = lane + 64 * i;
        p1w[idx] = fast_tanh(ord2f(__float_as_uint(p1w[idx])));
    }
    if (lane < 32) {
        int idx = lane + 64 * 17;
        p1w[idx] = fast_tanh(ord2f(__float_as_uint(p1w[idx])));
    }

    // ---- conv2 partial: group g = 2sl+rs; 16 f2 as 8 packed pairs ----
    // main chunks m=0,1 (t=0..127, all lanes useful); t=128..134 via per-lane tail.
    const int g = 2 * sl + rs;
    const v2f* b2v = (const v2f*)(b2c + sl * 16);
    v2f a2v[8][2];
#pragma unroll
    for (int j = 0; j < 8; ++j) {
        v2f bz = rs ? (v2f){0.f, 0.f} : b2v[j];   // pre-folded bias counted once
        a2v[j][0] = bz; a2v[j][1] = bz;
    }

#pragma unroll 1
    for (int ic = 0; ic < 8; ++ic) {
        const float* src = p1w + ic * 140;   // logical t' = idx - 4
        float win[2][5];                     // straight-line, all offsets compile-time
#pragma unroll
        for (int m = 0; m < 2; ++m) {
#pragma unroll
            for (int k = 0; k < 5; ++k) win[m][k] = src[lane + 64 * m + k];
        }
#pragma unroll
        for (int k = 0; k < 5; ++k) {
            const v2f* wv2 = (const v2f*)(w2t + ((g * 8 + ic) * 5 + k) * 16);
            v2f s0 = { win[0][k], win[0][k] };
            v2f s1 = { win[1][k], win[1][k] };
#pragma unroll
            for (int j = 0; j < 8; ++j) {
                v2f w = wv2[j];
                a2v[j][0] = fma2(w, s0, a2v[j][0]);
                a2v[j][1] = fma2(w, s1, a2v[j][1]);
            }
        }
    }

    // per-lane tail: lanes 0..55 each own (t = 128+tt, f2-pair tj)
    const int tt = lane >> 3;                // 0..7 (7 = inactive)
    const int tj = lane & 7;
    v2f at = (!rs) ? b2v[tj] : (v2f){0.f, 0.f};
    {
        const float* tsrc0 = p1w + 128 + tt;             // + ic*140 + k (imm)
        const float* tw    = w2t + g * 640 + 2 * tj;     // + (ic*5+k)*16 (imm)
#pragma unroll
        for (int ic = 0; ic < 8; ++ic) {
#pragma unroll
            for (int k = 0; k < 5; ++k) {
                float sv = tsrc0[ic * 140 + k];          // <=139: in-region even for tt=7
                v2f w = *(const v2f*)(tw + (ic * 5 + k) * 16);
                v2f sb = { sv, sv };
                at = fma2(w, sb, at);
            }
        }
    }

    // ---- cross-wave fold (a2 sum) in the pair's dead p1 regions ----
    float* scr = uni + (wv & ~1) * WREG;     // 2240 floats >= 16*137
    __syncthreads();                          // both halves' conv2 done
    if (rs) {
#pragma unroll
        for (int j = 0; j < 8; ++j) {
            scr[(2 * j) * 137 + lane]           = a2v[j][0].x;
            scr[(2 * j + 1) * 137 + lane]       = a2v[j][0].y;
            scr[(2 * j) * 137 + lane + 64]      = a2v[j][1].x;
            scr[(2 * j + 1) * 137 + lane + 64]  = a2v[j][1].y;
        }
        if (lane < 56) {
            scr[(2 * tj) * 137 + 128 + tt]     = at.x;
            scr[(2 * tj + 1) * 137 + 128 + tt] = at.y;
        }
    }
    __syncthreads();
    if (!rs) {
#pragma unroll
        for (int j = 0; j < 8; ++j) {
            scr[(2 * j) * 137 + lane]           += a2v[j][0].x;
            scr[(2 * j + 1) * 137 + lane]       += a2v[j][0].y;
            scr[(2 * j) * 137 + lane + 64]      += a2v[j][1].x;
            scr[(2 * j + 1) * 137 + lane + 64]  += a2v[j][1].y;
        }
        if (lane < 56) {
            scr[(2 * tj) * 137 + 128 + tt]     += at.x;
            scr[(2 * tj + 1) * 137 + 128 + tt] += at.y;
        }
    }
    __syncthreads();                          // sums visible to both waves

    // ---- top-4 (float path): value desc, tie -> lower t; 8 lanes per f2 ----
    // pass1: per-lane sorted top-4 (v_max/min_f32 bubble) + butterfly merge.
    // pass2: thr = L3; gt/eq counts + packed group prefix; ordered emit at
    // exact t-rank slot. Equal semantics to u64 keys (stable top_k).
    {
        const int f2o = (lane >> 3) + 8 * rs;  // this wave's 8 f2 channels
        const int seg = lane & 7;              // segment of 17 (last has 16)
        const float* src = scr + f2o * 137 + seg * 17;
        const float NINF = -__builtin_inff();
        float L0 = NINF, L1 = NINF, L2 = NINF, L3 = NINF;
#pragma unroll 1
        for (int i = 0; i < 16; ++i) {
            float v = src[i];
            float a0 = fmaxf(L0, v),  s0 = fminf(L0, v);  L0 = a0;
            float a1 = fmaxf(L1, s0), s1 = fminf(L1, s0); L1 = a1;
            float a2 = fmaxf(L2, s1), s2 = fminf(L2, s1); L2 = a2;
            L3 = fmaxf(L3, s2);
        }
        {                                      // 17th elem: invalid only for seg==7
            float v = (seg == 7) ? NINF : src[16];   // 135/136 = row slack, in-bounds
            float a0 = fmaxf(L0, v),  s0 = fminf(L0, v);  L0 = a0;
            float a1 = fmaxf(L1, s0), s1 = fminf(L1, s0); L1 = a1;
            float a2 = fmaxf(L2, s1), s2 = fminf(L2, s1); L2 = a2;
            L3 = fmaxf(L3, s2);
        }
        // merge 8 segments: 3 xor rounds; r_i = min_{j+l=i} max(A_j,B_l)
#pragma unroll
        for (int d = 1; d <= 4; d <<= 1) {
            float M0 = __shfl_xor(L0, d, 64), M1 = __shfl_xor(L1, d, 64);
            float M2 = __shfl_xor(L2, d, 64), M3 = __shfl_xor(L3, d, 64);
            float r0 = fmaxf(L0, M0);
            float r1 = fminf(fmaxf(L0, M1), fmaxf(L1, M0));
            float r2 = fminf(fminf(fmaxf(L0, M2), fmaxf(L1, M1)), fmaxf(L2, M0));
            float r3 = fminf(fminf(fmaxf(L0, M3), fmaxf(L1, M2)),
                             fminf(fmaxf(L2, M1), fmaxf(L3, M0)));
            L0 = r0; L1 = r1; L2 = r2; L3 = r3;
        }
        const float thr = L3;
        const int total_gt = (int)(L0 > thr) + (int)(L1 > thr) + (int)(L2 > thr);
        const int need = 4 - total_gt;         // #thr-ties kept (earliest t), >=1
        // per-lane counts over own segment
        int ngt = 0, neq = 0;
#pragma unroll 1
        for (int i = 0; i < 16; ++i) {
            float v = src[i];
            ngt += (v > thr); neq += (v == thr);
        }
        if (seg != 7) {
            float v = src[16];
            ngt += (v > thr); neq += (v == thr);
        }
        // packed inclusive prefix across the 8-seg group (counts <= 17 < 256)
        int packed = (ngt << 8) | neq;
        int incl = packed;
#pragma unroll
        for (int d = 1; d <= 4; d <<= 1) {
            int y = __shfl_up(incl, d, 8);
            if (seg >= d) incl += y;
        }
        const int pgt = (incl >> 8) - ngt;     // exclusive prefixes
        const int peq = (incl & 0xFF) - neq;
        int slot = pgt + ((peq < need) ? peq : need);   // this lane's first out slot
        int eqseen = peq;
        float* qp = &p2loc[(wv >> 1) * 64 + f2o * 4];
#pragma unroll 1
        for (int i = 0; i < 16; ++i) {
            float v = src[i];
            bool isgt = v > thr;
            bool iseq = (v == thr);
            bool keep = isgt || (iseq && (eqseen < need));
            if (keep) qp[slot++] = v;
            eqseen += iseq;
        }
        if (seg != 7) {
            float v = src[16];
            bool keep = (v > thr) || ((v == thr) && (eqseen < need));
            if (keep) qp[slot] = v;
        }
    }
    __syncthreads();

    // ---- FC partials over 128 features, all 4 waves (3 classes x 64 feats each) ----
    {
        const int nb = (wv >> 1) * 3;          // class base: 0 or 3
        const int fh = (wv & 1) * 64;          // feature half
        float pv = fast_tanh(p2loc[fh + lane]);
#pragma unroll
        for (int i = 0; i < 3; ++i) {
            float s = pv * fcw[(nb + i) * 1024 + q8 * 128 + fh + lane];
#pragma unroll
            for (int off = 32; off > 0; off >>= 1) s += __shfl_xor(s, off, 64);
            if (lane == 0) fred[wv][i] = s;
        }
    }
    __syncthreads();
    if (tid < 6) {
        float v = (tid < 3) ? (fred[0][tid] + fred[1][tid])
                            : (fred[2][tid - 3] + fred[3][tid - 3]);
        atomicAdd(&out[sample * 6 + tid], v);
    }
}

extern "C" void kernel_launch(void* const* d_in, const int* in_sizes, int n_in,
                              void* d_out, int out_size, void* d_ws, size_t ws_size,
                              hipStream_t stream) {
    (void)in_sizes; (void)n_in; (void)out_size; (void)ws_size;
    const int*   x   = (const int*)d_in[0];
    const float* emb = (const float*)d_in[1];
    const float* w1  = (const float*)d_in[2];
    const float* b1  = (const float*)d_in[3];
    const float* w2  = (const float*)d_in[4];
    const float* b2  = (const float*)d_in[5];
    const float* fcw = (const float*)d_in[6];
    const float* fcb = (const float*)d_in[7];
    float* outp = (float*)d_out;
    float* wsf  = (float*)d_ws;   // weights+biases: 24576 floats

    dcnn_prep<<<96, 256, 0, stream>>>(w1, b1, w2, b2, fcb, outp, wsf);
    dcnn_main<<<4096, 256, 0, stream>>>(x, emb, fcw, wsf, outp);
}